// Round 14
// baseline (411.242 us; speedup 1.0000x reference)
//
#include <hip/hip_runtime.h>

#define NN 32      // nodes
#define FF 64      // GAT out features
#define HH 128     // LSTM hidden
#define G4 512     // 4*H
#define BB 32      // batch
#define TT 512     // time steps
#define ET 128     // 96 edges + 32 self loops
#define NPOS (BB*TT)

__device__ __forceinline__ float frcp(float x) { return __builtin_amdgcn_rcpf(x); }

// ---------------- prep: fold GAT linear into LSTM input weights + Wt transpose ----------------
// R11 (verified) layout for lstm thread tid=r2*8+ko: 128 floats = [c(8)][kk(16)],
// col(c) = (c&3)*128 + 2*r2 + (c>>2), k = ko*16 + kk.  Note acc index c == lane ko's
// (row,gate) when c = (ko>>2)*4 + (ko&3)... i.e. c == ko. Used by the cndmask tree.
__global__ __launch_bounds__(512) void prep_kernel(const float* __restrict__ w_gat,
                                                   const float* __restrict__ b_gat,
                                                   const float* __restrict__ W_ih,
                                                   const float* __restrict__ W_hh,
                                                   float* __restrict__ W_eff,
                                                   float* __restrict__ biasp,
                                                   float* __restrict__ Wt) {
  int j = threadIdx.x;
  int n = blockIdx.x;
  float accw = 0.f, accb = 0.f;
#pragma unroll 8
  for (int f = 0; f < FF; ++f) {
    float wv = W_ih[(n * FF + f) * G4 + j];
    accw = fmaf(w_gat[f], wv, accw);
    accb = fmaf(b_gat[f], wv, accb);
  }
  W_eff[n * G4 + j] = accw;
  biasp[n * G4 + j] = accb;
  int g0 = (n * G4 + j) * 4;
#pragma unroll
  for (int q = 0; q < 4; ++q) {
    int e = g0 + q;
    int tl = e >> 7, idx = e & 127;
    int r2 = tl >> 3, ko = tl & 7;
    int c = idx >> 4, kk = idx & 15;
    int row = 2 * r2 + (c >> 2);
    int col = (c & 3) * 128 + row;
    Wt[e] = W_hh[(ko * 16 + kk) * G4 + col];
  }
}

// ---------------- fused GAT + xw (+ block-local bias/sort/scal) ----------------
__global__ __launch_bounds__(256) void gatxw_kernel(const float* __restrict__ x_seq,
                                                    const int* __restrict__ ei,
                                                    const float* __restrict__ w_gat,
                                                    const float* __restrict__ att_src,
                                                    const float* __restrict__ att_dst,
                                                    const float* __restrict__ b_ih,
                                                    const float* __restrict__ b_hh,
                                                    const float* __restrict__ W_eff,
                                                    const float* __restrict__ biasp,
                                                    float* __restrict__ xw) {
  __shared__ int srt[ET];
  __shared__ int offs[NN + 1];
  __shared__ int cnt[NN];
  __shared__ float xs[256];
  __shared__ float sl[256];
  __shared__ float scal_sh[2];
  int tid = threadIdx.x;
  int posbase = blockIdx.x * 8;
  float we0[NN], we1[NN];
#pragma unroll
  for (int nn = 0; nn < NN; ++nn) {
    we0[nn] = W_eff[nn * G4 + tid];
    we1[nn] = W_eff[nn * G4 + 256 + tid];
  }
  float b0 = b_ih[tid] + b_hh[tid];
  float b1 = b_ih[256 + tid] + b_hh[256 + tid];
#pragma unroll 8
  for (int n = 0; n < NN; ++n) {
    b0 += biasp[n * G4 + tid];
    b1 += biasp[n * G4 + 256 + tid];
  }
  if (tid < NN) cnt[tid] = 0;
  __syncthreads();
  int es = 0, ed = 0, tk = 0;
  if (tid < ET) {
    if (tid < 96) { es = ei[tid]; ed = ei[96 + tid]; }
    else { es = tid - 96; ed = tid - 96; }
    tk = atomicAdd(&cnt[ed], 1);
  }
  __syncthreads();
  if (tid == 0) {
    offs[0] = 0;
    for (int n = 0; n < NN; ++n) offs[n + 1] = offs[n] + cnt[n];
  }
  if (tid == 1) {
    float cs = 0.f, cd = 0.f;
    for (int f = 0; f < FF; ++f) {
      cs = fmaf(w_gat[f], att_src[f], cs);
      cd = fmaf(w_gat[f], att_dst[f], cd);
    }
    scal_sh[0] = cs;
    scal_sh[1] = cd;
  }
  __syncthreads();
  if (tid < ET) srt[offs[ed] + tk] = es;
  xs[tid] = x_seq[posbase * NN + tid];  // coalesced
  __syncthreads();
  float cs = scal_sh[0], cd = scal_sh[1];
  int p = tid >> 5, n = tid & 31;
  int base = p * 32;
  int e0 = offs[n], e1 = offs[n + 1];
  float xn = xs[base + n];
  float cdxn = cd * xn;
  float m = -3.0e38f;
  for (int e = e0; e < e1; ++e) {
    float ev = fmaf(cs, xs[base + srt[e]], cdxn);
    ev = ev > 0.f ? ev : 0.2f * ev;  // LeakyReLU(0.2)
    m = fmaxf(m, ev);
  }
  float z = 0.f, sa = 0.f;
  for (int e = e0; e < e1; ++e) {
    float xsv = xs[base + srt[e]];
    float ev = fmaf(cs, xsv, cdxn);
    ev = ev > 0.f ? ev : 0.2f * ev;
    float ex = __expf(ev - m);
    z += ex;
    sa = fmaf(ex, xsv, sa);
  }
  sl[p * 32 + n] = sa * frcp(z);
  __syncthreads();
  for (int pp = 0; pp < 8; ++pp) {
    const float4* sp = (const float4*)&sl[pp * 32];
    float a0 = b0, a1 = b1;
#pragma unroll
    for (int q = 0; q < 8; ++q) {
      float4 sv = sp[q];
      a0 = fmaf(sv.x, we0[4 * q], a0);
      a0 = fmaf(sv.y, we0[4 * q + 1], a0);
      a0 = fmaf(sv.z, we0[4 * q + 2], a0);
      a0 = fmaf(sv.w, we0[4 * q + 3], a0);
      a1 = fmaf(sv.x, we1[4 * q], a1);
      a1 = fmaf(sv.y, we1[4 * q + 1], a1);
      a1 = fmaf(sv.z, we1[4 * q + 2], a1);
      a1 = fmaf(sv.w, we1[4 * q + 3], a1);
    }
    size_t row = (size_t)(posbase + pp) * G4;
    xw[row + tid] = a0;
    xw[row + 256 + tid] = a1;
  }
}

// ---------------- LSTM scan: C=8 (R11 core) + gate-split activation (R13 tail) ----------------
// tid=r2*8+ko: 8 cols (2 rows x 4 gates), k in [16ko,16ko+16). 4 ds_read_b128
// (32 KB/step vs 64 at C=4). Full 3-round butterfly (24 DPP) then 7-cndmask
// tree selects lane ko's own (row,gate) sum (acc c == ko), +x, ONE activation
// per lane, 4 quad-broadcast DPP regather, c/h per quad. Hazard nops per R12
// lesson (trans->VALU: 1 wait; VALU->DPP same reg: 2 waits — 8-reg interleave
// covers the butterfly naturally).

#define PK8F(HP, W0, W1, W2, W3, W4, W5, W6, W7) \
  "v_pk_fma_f32 v[192:193], v[" HP "], v[" W0 "], 0\n\t" \
  "v_pk_fma_f32 v[194:195], v[" HP "], v[" W1 "], 0\n\t" \
  "v_pk_fma_f32 v[196:197], v[" HP "], v[" W2 "], 0\n\t" \
  "v_pk_fma_f32 v[198:199], v[" HP "], v[" W3 "], 0\n\t" \
  "v_pk_fma_f32 v[200:201], v[" HP "], v[" W4 "], 0\n\t" \
  "v_pk_fma_f32 v[202:203], v[" HP "], v[" W5 "], 0\n\t" \
  "v_pk_fma_f32 v[204:205], v[" HP "], v[" W6 "], 0\n\t" \
  "v_pk_fma_f32 v[206:207], v[" HP "], v[" W7 "], 0\n\t"

#define PK8A(HP, W0, W1, W2, W3, W4, W5, W6, W7) \
  "v_pk_fma_f32 v[192:193], v[" HP "], v[" W0 "], v[192:193]\n\t" \
  "v_pk_fma_f32 v[194:195], v[" HP "], v[" W1 "], v[194:195]\n\t" \
  "v_pk_fma_f32 v[196:197], v[" HP "], v[" W2 "], v[196:197]\n\t" \
  "v_pk_fma_f32 v[198:199], v[" HP "], v[" W3 "], v[198:199]\n\t" \
  "v_pk_fma_f32 v[200:201], v[" HP "], v[" W4 "], v[200:201]\n\t" \
  "v_pk_fma_f32 v[202:203], v[" HP "], v[" W5 "], v[202:203]\n\t" \
  "v_pk_fma_f32 v[204:205], v[" HP "], v[" W6 "], v[204:205]\n\t" \
  "v_pk_fma_f32 v[206:207], v[" HP "], v[" W7 "], v[206:207]\n\t"

#define DPP8(CTRL) \
  "v_add_f32_dpp v208, v208, v208 " CTRL " row_mask:0xf bank_mask:0xf\n\t" \
  "v_add_f32_dpp v209, v209, v209 " CTRL " row_mask:0xf bank_mask:0xf\n\t" \
  "v_add_f32_dpp v210, v210, v210 " CTRL " row_mask:0xf bank_mask:0xf\n\t" \
  "v_add_f32_dpp v211, v211, v211 " CTRL " row_mask:0xf bank_mask:0xf\n\t" \
  "v_add_f32_dpp v212, v212, v212 " CTRL " row_mask:0xf bank_mask:0xf\n\t" \
  "v_add_f32_dpp v213, v213, v213 " CTRL " row_mask:0xf bank_mask:0xf\n\t" \
  "v_add_f32_dpp v214, v214, v214 " CTRL " row_mask:0xf bank_mask:0xf\n\t" \
  "v_add_f32_dpp v215, v215, v215 " CTRL " row_mask:0xf bank_mask:0xf\n\t"

#define PHASE(XSLOT, O0, O1, O2, O3, WO) \
  "ds_read_b128 v[32:35], v237 offset:" O0 "\n\t" \
  "ds_read_b128 v[36:39], v237 offset:" O1 "\n\t" \
  "ds_read_b128 v[40:43], v237 offset:" O2 "\n\t" \
  "ds_read_b128 v[44:47], v237 offset:" O3 "\n\t" \
  "s_waitcnt lgkmcnt(3)\n\t" \
  PK8F("32:33", "64:65", "80:81", "96:97", "112:113", "128:129", "144:145", "160:161", "176:177") \
  PK8A("34:35", "66:67", "82:83", "98:99", "114:115", "130:131", "146:147", "162:163", "178:179") \
  "s_waitcnt lgkmcnt(2)\n\t" \
  PK8A("36:37", "68:69", "84:85", "100:101", "116:117", "132:133", "148:149", "164:165", "180:181") \
  PK8A("38:39", "70:71", "86:87", "102:103", "118:119", "134:135", "150:151", "166:167", "182:183") \
  "s_waitcnt lgkmcnt(1)\n\t" \
  PK8A("40:41", "72:73", "88:89", "104:105", "120:121", "136:137", "152:153", "168:169", "184:185") \
  PK8A("42:43", "74:75", "90:91", "106:107", "122:123", "138:139", "154:155", "170:171", "186:187") \
  "s_waitcnt lgkmcnt(0)\n\t" \
  PK8A("44:45", "76:77", "92:93", "108:109", "124:125", "140:141", "156:157", "172:173", "188:189") \
  PK8A("46:47", "78:79", "94:95", "110:111", "126:127", "142:143", "158:159", "174:175", "190:191") \
  "s_waitcnt vmcnt(3)\n\t" \
  "v_mov_b32 v240, " XSLOT "\n\t" \
  "global_load_dword " XSLOT ", v236, %[xwb]\n\t" \
  "v_add_u32 v236, 0x800, v236\n\t" \
  "v_add_f32 v208, v192, v193\n\t" \
  "v_add_f32 v209, v194, v195\n\t" \
  "v_add_f32 v210, v196, v197\n\t" \
  "v_add_f32 v211, v198, v199\n\t" \
  "v_add_f32 v212, v200, v201\n\t" \
  "v_add_f32 v213, v202, v203\n\t" \
  "v_add_f32 v214, v204, v205\n\t" \
  "v_add_f32 v215, v206, v207\n\t" \
  DPP8("quad_perm:[1,0,3,2]") \
  DPP8("quad_perm:[2,3,0,1]") \
  DPP8("row_half_mirror") \
  "v_cndmask_b32 v216, v208, v209, s[22:23]\n\t" \
  "v_cndmask_b32 v217, v210, v211, s[22:23]\n\t" \
  "v_cndmask_b32 v218, v212, v213, s[22:23]\n\t" \
  "v_cndmask_b32 v219, v214, v215, s[22:23]\n\t" \
  "v_cndmask_b32 v216, v216, v217, s[24:25]\n\t" \
  "v_cndmask_b32 v218, v218, v219, s[24:25]\n\t" \
  "v_cndmask_b32 v216, v216, v218, s[26:27]\n\t" \
  "v_add_f32 v216, v216, v240\n\t" \
  "v_mul_f32 v217, v228, v216\n\t" \
  "v_exp_f32 v217, v217\n\t" \
  "s_nop 0\n\t" \
  "v_add_f32 v217, 1.0, v217\n\t" \
  "v_rcp_f32 v217, v217\n\t" \
  "s_nop 0\n\t" \
  "v_fma_f32 v218, v229, v217, v230\n\t" \
  "s_nop 1\n\t" \
  "v_add_f32_dpp v219, v218, v231 quad_perm:[0,0,0,0] row_mask:0xf bank_mask:0xf\n\t" \
  "v_add_f32_dpp v220, v218, v231 quad_perm:[1,1,1,1] row_mask:0xf bank_mask:0xf\n\t" \
  "v_add_f32_dpp v221, v218, v231 quad_perm:[2,2,2,2] row_mask:0xf bank_mask:0xf\n\t" \
  "v_add_f32_dpp v222, v218, v231 quad_perm:[3,3,3,3] row_mask:0xf bank_mask:0xf\n\t" \
  "v_mul_f32 v219, v219, v221\n\t" \
  "v_fma_f32 v239, v220, v239, v219\n\t" \
  "v_mul_f32 v217, 0x4038aa3b, v239\n\t" \
  "v_exp_f32 v217, v217\n\t" \
  "s_nop 0\n\t" \
  "v_add_f32 v217, 1.0, v217\n\t" \
  "v_rcp_f32 v217, v217\n\t" \
  "s_nop 0\n\t" \
  "v_fma_f32 v217, -2.0, v217, 1.0\n\t" \
  "v_mul_f32 v217, v222, v217\n\t" \
  "ds_write_b32 v238, v217 offset:" WO "\n\t" \
  "s_waitcnt lgkmcnt(0)\n\t" \
  "s_barrier\n\t"

__global__ __launch_bounds__(512, 2) void lstm_kernel(const float* __restrict__ xw,
                                                      const float* __restrict__ Wt,
                                                      const float* __restrict__ W_fc,
                                                      const float* __restrict__ b_fc,
                                                      float* __restrict__ out) {
  __shared__ __align__(16) float lds[320];  // hA [0,160) floats, hB [160,320)
  int b = blockIdx.x, tid = threadIdx.x;
  int r2 = tid >> 3, ko = tid & 7;
  if (tid < 320) lds[tid] = 0.f;
  const float* xwb = xw + (size_t)b * TT * G4;
  int myrow = 2 * r2 + (ko >> 2);
  unsigned xoff0 = (unsigned)((((ko & 3) * 128) + myrow) * 4);  // t=0
  unsigned wtoff = (unsigned)(tid * 512);
  unsigned lbase = (unsigned)(uintptr_t)&lds[0];  // LDS aperture is 4GB-aligned
  unsigned rda = lbase + (unsigned)(ko * 80);     // region ko, 20-float stride
  unsigned wra = lbase + (unsigned)(((myrow >> 4) * 20 + (myrow & 15)) * 4);
  // gate-split act constants: gate = ko&3 (i,f,o sigmoid; g=2 tanh)
  int gate = ko & 3;
  float kmulf = (gate == 2) ? __uint_as_float(0x4038aa3bu)   //  2*log2e
                            : __uint_as_float(0xbfb8aa3bu);  // -log2e
  float Af = (gate == 2) ? -2.f : 1.f;
  float Bf = (gate == 2) ? 1.f : 0.f;
  unsigned kb0 = ko & 1, kb1 = (ko >> 1) & 1, kb2 = ko >> 2;
  __syncthreads();
  asm volatile(
    "v_mov_b32 v236, %[xo]\n\t"
    "v_mov_b32 v237, %[rda]\n\t"
    "v_mov_b32 v238, %[wra]\n\t"
    "v_mov_b32 v239, 0\n\t"          // c
    "v_mov_b32 v228, %[km]\n\t"      // kmul
    "v_mov_b32 v229, %[Aa]\n\t"      // A
    "v_mov_b32 v230, %[Bb]\n\t"      // B
    "v_mov_b32 v231, 0\n\t"          // zero (DPP-gather src1)
    "v_cmp_eq_u32 s[22:23], 1, %[b0]\n\t"
    "v_cmp_eq_u32 s[24:25], 1, %[b1]\n\t"
    "v_cmp_eq_u32 s[26:27], 1, %[b2]\n\t"
    // x prefetch ring: t=0..3 -> v224..v227
    "global_load_dword v224, v236, %[xwb]\n\t"
    "v_add_u32 v236, 0x800, v236\n\t"
    "global_load_dword v225, v236, %[xwb]\n\t"
    "v_add_u32 v236, 0x800, v236\n\t"
    "global_load_dword v226, v236, %[xwb]\n\t"
    "v_add_u32 v236, 0x800, v236\n\t"
    "global_load_dword v227, v236, %[xwb]\n\t"
    "v_add_u32 v236, 0x800, v236\n\t"
    "global_load_dwordx4 v[64:67], %[wto], %[wtb] offset:0\n\t"
    "global_load_dwordx4 v[68:71], %[wto], %[wtb] offset:16\n\t"
    "global_load_dwordx4 v[72:75], %[wto], %[wtb] offset:32\n\t"
    "global_load_dwordx4 v[76:79], %[wto], %[wtb] offset:48\n\t"
    "global_load_dwordx4 v[80:83], %[wto], %[wtb] offset:64\n\t"
    "global_load_dwordx4 v[84:87], %[wto], %[wtb] offset:80\n\t"
    "global_load_dwordx4 v[88:91], %[wto], %[wtb] offset:96\n\t"
    "global_load_dwordx4 v[92:95], %[wto], %[wtb] offset:112\n\t"
    "global_load_dwordx4 v[96:99], %[wto], %[wtb] offset:128\n\t"
    "global_load_dwordx4 v[100:103], %[wto], %[wtb] offset:144\n\t"
    "global_load_dwordx4 v[104:107], %[wto], %[wtb] offset:160\n\t"
    "global_load_dwordx4 v[108:111], %[wto], %[wtb] offset:176\n\t"
    "global_load_dwordx4 v[112:115], %[wto], %[wtb] offset:192\n\t"
    "global_load_dwordx4 v[116:119], %[wto], %[wtb] offset:208\n\t"
    "global_load_dwordx4 v[120:123], %[wto], %[wtb] offset:224\n\t"
    "global_load_dwordx4 v[124:127], %[wto], %[wtb] offset:240\n\t"
    "global_load_dwordx4 v[128:131], %[wto], %[wtb] offset:256\n\t"
    "global_load_dwordx4 v[132:135], %[wto], %[wtb] offset:272\n\t"
    "global_load_dwordx4 v[136:139], %[wto], %[wtb] offset:288\n\t"
    "global_load_dwordx4 v[140:143], %[wto], %[wtb] offset:304\n\t"
    "global_load_dwordx4 v[144:147], %[wto], %[wtb] offset:320\n\t"
    "global_load_dwordx4 v[148:151], %[wto], %[wtb] offset:336\n\t"
    "global_load_dwordx4 v[152:155], %[wto], %[wtb] offset:352\n\t"
    "global_load_dwordx4 v[156:159], %[wto], %[wtb] offset:368\n\t"
    "global_load_dwordx4 v[160:163], %[wto], %[wtb] offset:384\n\t"
    "global_load_dwordx4 v[164:167], %[wto], %[wtb] offset:400\n\t"
    "global_load_dwordx4 v[168:171], %[wto], %[wtb] offset:416\n\t"
    "global_load_dwordx4 v[172:175], %[wto], %[wtb] offset:432\n\t"
    "global_load_dwordx4 v[176:179], %[wto], %[wtb] offset:448\n\t"
    "global_load_dwordx4 v[180:183], %[wto], %[wtb] offset:464\n\t"
    "global_load_dwordx4 v[184:187], %[wto], %[wtb] offset:480\n\t"
    "global_load_dwordx4 v[188:191], %[wto], %[wtb] offset:496\n\t"
    "s_waitcnt vmcnt(0)\n\t"
    "s_movk_i32 s20, 0x80\n\t"    // 128 iterations x 4 phases = 512 steps
    "L_lstm_%=:\n\t"
    PHASE("v224", "0",   "16",  "32",  "48",  "640")   // read A, write B
    PHASE("v225", "640", "656", "672", "688", "0")     // read B, write A
    PHASE("v226", "0",   "16",  "32",  "48",  "640")
    PHASE("v227", "640", "656", "672", "688", "0")
    "s_sub_u32 s20, s20, 1\n\t"
    "s_cmp_lg_u32 s20, 0\n\t"
    "s_cbranch_scc1 L_lstm_%=\n\t"
    "s_waitcnt vmcnt(0) lgkmcnt(0)\n\t"
    :
    : [xwb]"s"(xwb), [wtb]"s"(Wt), [wto]"v"(wtoff), [xo]"v"(xoff0),
      [rda]"v"(rda), [wra]"v"(wra),
      [km]"v"(kmulf), [Aa]"v"(Af), [Bb]"v"(Bf),
      [b0]"v"(kb0), [b1]"v"(kb1), [b2]"v"(kb2)
    : "memory", "scc", "s20", "s22", "s23", "s24", "s25", "s26", "s27",
      "v32","v33","v34","v35","v36","v37","v38","v39",
      "v40","v41","v42","v43","v44","v45","v46","v47",
      "v64","v65","v66","v67","v68","v69","v70","v71",
      "v72","v73","v74","v75","v76","v77","v78","v79",
      "v80","v81","v82","v83","v84","v85","v86","v87",
      "v88","v89","v90","v91","v92","v93","v94","v95",
      "v96","v97","v98","v99","v100","v101","v102","v103",
      "v104","v105","v106","v107","v108","v109","v110","v111",
      "v112","v113","v114","v115","v116","v117","v118","v119",
      "v120","v121","v122","v123","v124","v125","v126","v127",
      "v128","v129","v130","v131","v132","v133","v134","v135",
      "v136","v137","v138","v139","v140","v141","v142","v143",
      "v144","v145","v146","v147","v148","v149","v150","v151",
      "v152","v153","v154","v155","v156","v157","v158","v159",
      "v160","v161","v162","v163","v164","v165","v166","v167",
      "v168","v169","v170","v171","v172","v173","v174","v175",
      "v176","v177","v178","v179","v180","v181","v182","v183",
      "v184","v185","v186","v187","v188","v189","v190","v191",
      "v192","v193","v194","v195","v196","v197","v198","v199",
      "v200","v201","v202","v203","v204","v205","v206","v207",
      "v208","v209","v210","v211","v212","v213","v214","v215",
      "v216","v217","v218","v219","v220","v221","v222","v223",
      "v224","v225","v226","v227","v228","v229","v230","v231",
      "v236","v237","v238","v239","v240");
  __syncthreads();
  // final h (t=511 wrote buffer A): h[k] at lds[(k>>4)*20 + (k&15)]
  if (tid < 4) {
    float acc = b_fc[tid];
#pragma unroll 8
    for (int k = 0; k < HH; ++k)
      acc = fmaf(lds[(k >> 4) * 20 + (k & 15)], W_fc[k * 4 + tid], acc);
    out[b * 4 + tid] = acc;
  }
}

extern "C" void kernel_launch(void* const* d_in, const int* in_sizes, int n_in,
                              void* d_out, int out_size, void* d_ws, size_t ws_size,
                              hipStream_t stream) {
  const float* x_seq   = (const float*)d_in[0];
  const int*   ei      = (const int*)d_in[1];
  const float* w_gat   = (const float*)d_in[2];
  const float* att_src = (const float*)d_in[3];
  const float* att_dst = (const float*)d_in[4];
  const float* b_gat   = (const float*)d_in[5];
  const float* W_ih    = (const float*)d_in[6];
  const float* W_hh    = (const float*)d_in[7];
  const float* b_ih    = (const float*)d_in[8];
  const float* b_hh    = (const float*)d_in[9];
  const float* W_fc    = (const float*)d_in[10];
  const float* b_fc    = (const float*)d_in[11];

  float* ws = (float*)d_ws;
  float* Wt    = ws;                            // 512*128 = 65536 f (16B-aligned)
  float* xw    = Wt + 65536;                    // (16384+8)*512 f (pad rows: 4-deep prefetch)
  float* W_eff = xw + (size_t)(NPOS + 8) * G4;  // 32*512
  float* biasp = W_eff + NN * G4;               // 32*512

  prep_kernel<<<NN, G4, 0, stream>>>(w_gat, b_gat, W_ih, W_hh, W_eff, biasp, Wt);
  gatxw_kernel<<<NPOS / 8, 256, 0, stream>>>(x_seq, ei, w_gat, att_src, att_dst,
                                             b_ih, b_hh, W_eff, biasp, xw);
  lstm_kernel<<<BB, G4, 0, stream>>>(xw, Wt, W_fc, b_fc, (float*)d_out);
}